// Round 2
// baseline (110.978 us; speedup 1.0000x reference)
//
#include <hip/hip_runtime.h>
#include <math.h>

typedef _Float16 f16;
typedef _Float16 f16x8 __attribute__((ext_vector_type(8)));
typedef float f32x4 __attribute__((ext_vector_type(4)));

// Problem constants (fixed by reference setup_inputs)
namespace {
constexpr int Bn = 4;     // batch
constexpr int Cn = 64;    // in channels
constexpr int On = 64;    // out channels
constexpr int Hn = 128;
constexpr int Wn = 128;
constexpr int Kn = 9;     // 3x3 taps
constexpr int HWn = Hn * Wn;          // 16384
constexpr int NPIX = Bn * HWn;        // 65536
constexpr int SR = 72;                // padded LDS row stride (halves): 64+8
}

// ---------------------------------------------------------------------------
// Kernel 1: transpose x [B][C][H][W] f32 -> xt [B][H*W][C] f16 (channels-last)
// and (blocks 0..143) prep MFMA-ready f16 weight layouts:
//   wtb [(k*64+o)*64+c] = (f16) weight[(o*64+c)*9+k]   (36864 f16)
//   wofb[(k*32+o)*64+c] = (f16) w_off [(o*64+c)*9+k]   (o<18, else 0; 18432)
// ---------------------------------------------------------------------------
__global__ __launch_bounds__(256) void transpose_prep(
    const float* __restrict__ x, const float* __restrict__ w_off,
    const float* __restrict__ weight, f16* __restrict__ xt,
    f16* __restrict__ wofb, f16* __restrict__ wtb) {
  const int t = blockIdx.x * 256 + threadIdx.x;
  if (t < Kn * On * Cn) {  // 36864
    int c = t & 63, o = (t >> 6) & 63, k = t >> 12;
    wtb[t] = (f16)weight[((o << 6) + c) * 9 + k];
  }
  if (t < Kn * 32 * Cn) {  // 18432
    int c = t & 63, o = (t >> 6) & 31, k = t >> 11;
    float v = (o < 18) ? w_off[((o << 6) + c) * 9 + k] : 0.f;
    wofb[t] = (f16)v;
  }

  const int l = threadIdx.x & 63;
  const int cw = threadIdx.x >> 6;          // 0..3
  const int pixbase = blockIdx.x * 64;
  const int b = pixbase >> 14;
  const int hw = (pixbase & (HWn - 1)) + l;

  f16x8 v0, v1;
#pragma unroll
  for (int i = 0; i < 8; ++i) {
    v0[i] = (f16)x[((size_t)(b * Cn + cw * 16 + i)) * HWn + hw];
    v1[i] = (f16)x[((size_t)(b * Cn + cw * 16 + 8 + i)) * HWn + hw];
  }
  f16* dst = xt + ((size_t)(b * HWn + hw)) * 64 + cw * 16;
  *(f16x8*)dst = v0;
  *(f16x8*)(dst + 8) = v1;
}

// Named-field register tile for one tap's bilinear corners (rule #20: no
// runtime-indexed register arrays).
struct Tap2 {
  f16x8 a0, a1, b0, b1, c0, c1, d0, d1;  // 4 corners x 2 halves
  float w00, w01, w10, w11;
};

// ---------------------------------------------------------------------------
// Kernel 2: fused offset-conv + DCN, one block = 64 consecutive px (same b,y).
// Pipeline per tap (both phases, fully unrolled so LDS buffer indices are
// compile-time and the compiler may overlap):
//   issue gathers for tap k+1 -> regs ; MFMA on Sb[k&1] ; combine + ds_write
//   tap k+1 -> Sb[1-(k&1)] ; barrier.
// This keeps the vmcnt wait for the gathers AFTER the MFMA block instead of
// serializing gather->write->MFMA (runtime 1-cur previously blocked reordering
// via alias analysis).
// ---------------------------------------------------------------------------
__global__ __launch_bounds__(256, 4) void dcn_fused(
    const f16* __restrict__ xt, const f16* __restrict__ wofb,
    const float* __restrict__ b_off, const f16* __restrict__ wtb,
    float* __restrict__ out) {
  __shared__ __align__(16) f16 Sb[2][64 * SR];     // 18432 B
  __shared__ __align__(16) float offL[64 * 18];    //  4608 B

  const int t = threadIdx.x;
  const int pixbase = blockIdx.x * 64;
  const int b = pixbase >> 14;
  const int y = (pixbase & (HWn - 1)) >> 7;
  const int xx0 = pixbase & (Wn - 1);              // 0 or 64
  const f16* xb = xt + (((size_t)b) << 14) * 64;

  const int px_s = t >> 2, cq = t & 3;             // staging role
  const int lane = t & 63, wv = t >> 6;            // gemm role
  const int l15 = lane & 15, q = lane >> 4;

  // ---------------- phase 1: offset GEMM ----------------
  const int m = wv & 1;                            // o-tile (0..1)
  const int nb = (wv >> 1) * 2;                    // first n-tile (0 or 2)

  auto load1 = [&](int k, f16x8& ra, f16x8& rb) {
    const int dy = k / 3 - 1, dx = k % 3 - 1;
    const int ys = y + dy, xs = xx0 + px_s + dx;
    if (ys >= 0 && ys < Hn && xs >= 0 && xs < Wn) {
      const f16* src = xb + (size_t)(ys * Wn + xs) * 64 + cq * 16;
      ra = *(const f16x8*)src;
      rb = *(const f16x8*)(src + 8);
    } else {
      ra = (f16x8){};
      rb = (f16x8){};
    }
  };
  auto write1 = [&](f16x8 ra, f16x8 rb, int buf) {
    f16* sdst = &Sb[buf][px_s * SR + cq * 16];
    *(f16x8*)sdst = ra;
    *(f16x8*)(sdst + 8) = rb;
  };

  f32x4 acc2[2] = {};
  f16x8 af[2], afn[2];
#pragma unroll
  for (int s = 0; s < 2; ++s)
    af[s] = *(const f16x8*)&wofb[(size_t)(m * 16 + l15) * 64 + s * 32 + q * 8];
  {
    f16x8 ra, rb;
    load1(0, ra, rb);
    write1(ra, rb, 0);
  }
  __syncthreads();
#pragma unroll
  for (int k = 0; k < Kn; ++k) {
    const int cur = k & 1;
    f16x8 nra, nrb;
    if (k + 1 < Kn) {
      load1(k + 1, nra, nrb);
#pragma unroll
      for (int s = 0; s < 2; ++s)
        afn[s] = *(const f16x8*)
            &wofb[(size_t)((k + 1) * 32 + m * 16 + l15) * 64 + s * 32 + q * 8];
    }
#pragma unroll
    for (int s = 0; s < 2; ++s) {
#pragma unroll
      for (int t2 = 0; t2 < 2; ++t2) {
        f16x8 bf = *(const f16x8*)
            &Sb[cur][((nb + t2) * 16 + l15) * SR + s * 32 + q * 8];
        acc2[t2] = __builtin_amdgcn_mfma_f32_16x16x32_f16(af[s], bf, acc2[t2],
                                                          0, 0, 0);
      }
    }
    if (k + 1 < Kn) write1(nra, nrb, 1 - cur);
    __syncthreads();
    af[0] = afn[0];
    af[1] = afn[1];
  }

  // phase-1 epilogue: C/D col=lane&15 (px), row=q*4+r (o). Write to LDS.
#pragma unroll
  for (int t2 = 0; t2 < 2; ++t2) {
#pragma unroll
    for (int r = 0; r < 4; ++r) {
      int o = m * 16 + q * 4 + r;
      if (o < 18) {
        int pxl = (nb + t2) * 16 + l15;
        offL[pxl * 18 + o] = acc2[t2][r] + b_off[o];
      }
    }
  }
  __syncthreads();

  // each thread grabs its pixel's 9 offset pairs from LDS
  float2 off9[9];
  {
    const float* op = &offL[px_s * 18];
#pragma unroll
    for (int k = 0; k < Kn; ++k) off9[k] = *(const float2*)(op + 2 * k);
  }

  // ---------------- phase 2: main DCN GEMM ----------------
  const int xx = xx0 + px_s;                      // this thread's pixel x
  const int obase = wv * 16;

  auto load2 = [&](int k, Tap2& tp) {
    const int dy = k / 3 - 1, dx = k % 3 - 1;
    float py = (float)(y + dy) + off9[k].x;
    float pxf = (float)(xx + dx) + off9[k].y;
    float y0f = floorf(py), x0f = floorf(pxf);
    int y0 = (int)y0f, x0 = (int)x0f;
    int y1 = y0 + 1, x1 = x0 + 1;
    float wy1 = py - y0f, wx1 = pxf - x0f;
    float wy0 = 1.f - wy1, wx0 = 1.f - wx1;
    float my0 = (y0 >= 0 && y0 < Hn) ? 1.f : 0.f;
    float my1 = (y1 >= 0 && y1 < Hn) ? 1.f : 0.f;
    float mx0 = (x0 >= 0 && x0 < Wn) ? 1.f : 0.f;
    float mx1 = (x1 >= 0 && x1 < Wn) ? 1.f : 0.f;
    tp.w00 = wy0 * wx0 * my0 * mx0;
    tp.w01 = wy0 * wx1 * my0 * mx1;
    tp.w10 = wy1 * wx0 * my1 * mx0;
    tp.w11 = wy1 * wx1 * my1 * mx1;
    int cy0 = min(max(y0, 0), Hn - 1), cy1 = min(max(y1, 0), Hn - 1);
    int cx0 = min(max(x0, 0), Wn - 1), cx1 = min(max(x1, 0), Wn - 1);
    const f16* r00 = xb + (size_t)(cy0 * Wn + cx0) * 64 + cq * 16;
    const f16* r01 = xb + (size_t)(cy0 * Wn + cx1) * 64 + cq * 16;
    const f16* r10 = xb + (size_t)(cy1 * Wn + cx0) * 64 + cq * 16;
    const f16* r11 = xb + (size_t)(cy1 * Wn + cx1) * 64 + cq * 16;
    tp.a0 = *(const f16x8*)r00;
    tp.a1 = *(const f16x8*)(r00 + 8);
    tp.b0 = *(const f16x8*)r01;
    tp.b1 = *(const f16x8*)(r01 + 8);
    tp.c0 = *(const f16x8*)r10;
    tp.c1 = *(const f16x8*)(r10 + 8);
    tp.d0 = *(const f16x8*)r11;
    tp.d1 = *(const f16x8*)(r11 + 8);
  };
  auto write2 = [&](const Tap2& tp, int buf) {
    f16* sdst = &Sb[buf][px_s * SR + cq * 16];
    f16x8 v0, v1;
#pragma unroll
    for (int i = 0; i < 8; ++i) {
      float s0 = tp.w00 * (float)tp.a0[i] + tp.w01 * (float)tp.b0[i] +
                 tp.w10 * (float)tp.c0[i] + tp.w11 * (float)tp.d0[i];
      float s1 = tp.w00 * (float)tp.a1[i] + tp.w01 * (float)tp.b1[i] +
                 tp.w10 * (float)tp.c1[i] + tp.w11 * (float)tp.d1[i];
      v0[i] = (f16)s0;
      v1[i] = (f16)s1;
    }
    *(f16x8*)sdst = v0;
    *(f16x8*)(sdst + 8) = v1;
  };

  f32x4 acc[4] = {};
  f16x8 wf[2], wfn[2];
#pragma unroll
  for (int s = 0; s < 2; ++s)
    wf[s] = *(const f16x8*)&wtb[(size_t)(obase + l15) * 64 + s * 32 + q * 8];
  {
    Tap2 tp;
    load2(0, tp);
    write2(tp, 0);
  }
  __syncthreads();
#pragma unroll
  for (int k = 0; k < Kn; ++k) {
    const int cur = k & 1;
    Tap2 tp;
    if (k + 1 < Kn) {
      load2(k + 1, tp);
#pragma unroll
      for (int s = 0; s < 2; ++s)
        wfn[s] = *(const f16x8*)
            &wtb[(size_t)((k + 1) * 64 + obase + l15) * 64 + s * 32 + q * 8];
    }
#pragma unroll
    for (int s = 0; s < 2; ++s) {
#pragma unroll
      for (int pt = 0; pt < 4; ++pt) {
        f16x8 bf =
            *(const f16x8*)&Sb[cur][(pt * 16 + l15) * SR + s * 32 + q * 8];
        acc[pt] = __builtin_amdgcn_mfma_f32_16x16x32_f16(wf[s], bf, acc[pt],
                                                         0, 0, 0);
      }
    }
    if (k + 1 < Kn) write2(tp, 1 - cur);
    __syncthreads();
    wf[0] = wfn[0];
    wf[1] = wfn[1];
  }

  // phase-2 epilogue: C/D layout col=lane&15 (px), row=q*4+reg (o in chunk)
  float* ob = out + (size_t)b * On * HWn + (pixbase & (HWn - 1));
#pragma unroll
  for (int pt = 0; pt < 4; ++pt) {
#pragma unroll
    for (int r = 0; r < 4; ++r) {
      int o = obase + q * 4 + r;
      ob[(size_t)o * HWn + pt * 16 + l15] = acc[pt][r];
    }
  }
}

// ---------------------------------------------------------------------------
extern "C" void kernel_launch(void* const* d_in, const int* in_sizes, int n_in,
                              void* d_out, int out_size, void* d_ws,
                              size_t ws_size, hipStream_t stream) {
  const float* x = (const float*)d_in[0];       // [4,64,128,128]
  const float* w_off = (const float*)d_in[1];   // [18,64,3,3]
  const float* b_off = (const float*)d_in[2];   // [18]
  const float* weight = (const float*)d_in[3];  // [64,64,3,3]
  float* out = (float*)d_out;                   // [4,64,128,128]

  // workspace layout (offset buffer lives in LDS)
  f16* xt = (f16*)d_ws;                         // 4,194,304 f16 = 8 MB
  f16* wtb = xt + (size_t)NPIX * Cn;            // 36,864 f16
  f16* wofb = wtb + Kn * On * Cn;               // 18,432 f16

  transpose_prep<<<dim3(NPIX / 64), dim3(256), 0, stream>>>(x, w_off, weight,
                                                            xt, wofb, wtb);
  dcn_fused<<<dim3(NPIX / 64), dim3(256), 0, stream>>>(xt, wofb, b_off, wtb,
                                                       out);
}

// Round 5
// 109.834 us; speedup vs baseline: 1.0104x; 1.0104x over previous
//
#include <hip/hip_runtime.h>
#include <math.h>

typedef _Float16 f16;
typedef _Float16 f16x8 __attribute__((ext_vector_type(8)));
typedef float f32x4 __attribute__((ext_vector_type(4)));
typedef unsigned int u32;
typedef unsigned int u32x4 __attribute__((ext_vector_type(4)));
typedef unsigned short u16;

// Problem constants (fixed by reference setup_inputs)
namespace {
constexpr int Bn = 4;     // batch
constexpr int Cn = 64;    // in channels
constexpr int On = 64;    // out channels
constexpr int Hn = 128;
constexpr int Wn = 128;
constexpr int Kn = 9;     // 3x3 taps
constexpr int HWn = Hn * Wn;          // 16384
constexpr int NPIX = Bn * HWn;        // 65536
constexpr int SR = 72;                // padded LDS row stride (halves): 64+8
}

// ---------------------------------------------------------------------------
// Kernel 1: transpose x [B][C][H][W] f32 -> xt [B][H*W][C] f16 (channels-last)
// and (blocks 0..143) prep MFMA-ready f16 weight layouts:
//   wtb [(k*64+o)*64+c] = (f16) weight[(o*64+c)*9+k]   (36864 f16)
//   wofb[(k*32+o)*64+c] = (f16) w_off [(o*64+c)*9+k]   (o<18, else 0; 18432)
// ---------------------------------------------------------------------------
__global__ __launch_bounds__(256) void transpose_prep(
    const float* __restrict__ x, const float* __restrict__ w_off,
    const float* __restrict__ weight, f16* __restrict__ xt,
    f16* __restrict__ wofb, f16* __restrict__ wtb) {
  const int t = blockIdx.x * 256 + threadIdx.x;
  if (t < Kn * On * Cn) {  // 36864
    int c = t & 63, o = (t >> 6) & 63, k = t >> 12;
    wtb[t] = (f16)weight[((o << 6) + c) * 9 + k];
  }
  if (t < Kn * 32 * Cn) {  // 18432
    int c = t & 63, o = (t >> 6) & 31, k = t >> 11;
    float v = (o < 18) ? w_off[((o << 6) + c) * 9 + k] : 0.f;
    wofb[t] = (f16)v;
  }

  const int l = threadIdx.x & 63;
  const int cw = threadIdx.x >> 6;          // 0..3
  const int pixbase = blockIdx.x * 64;
  const int b = pixbase >> 14;
  const int hw = (pixbase & (HWn - 1)) + l;

  f16x8 v0, v1;
#pragma unroll
  for (int i = 0; i < 8; ++i) {
    v0[i] = (f16)x[((size_t)(b * Cn + cw * 16 + i)) * HWn + hw];
    v1[i] = (f16)x[((size_t)(b * Cn + cw * 16 + 8 + i)) * HWn + hw];
  }
  f16* dst = xt + ((size_t)(b * HWn + hw)) * 64 + cw * 16;
  *(f16x8*)dst = v0;
  *(f16x8*)(dst + 8) = v1;
}

// Named-field register tile for one tap's bilinear corners (rule #20: no
// runtime-indexed register arrays). Weights held as 8-wide splat f16 vectors
// built from integer splat dwords ((h<<16)|h repeated), so the packed-f16
// combine is pure vector-vector v_pk ops -- no scalar broadcast / op_sel
// lowering anywhere (the round-3 broadcast variant miscompiled).
struct Tap2 {
  f16x8 a0, a1, b0, b1, c0, c1, d0, d1;  // 4 corners x 2 halves
  f16x8 W00, W01, W10, W11;              // splatted weights
};

static __device__ inline f16x8 splat8(float w) {
  u16 h = __builtin_bit_cast(u16, (f16)w);
  u32 p = ((u32)h << 16) | (u32)h;
  u32x4 v = {p, p, p, p};
  return __builtin_bit_cast(f16x8, v);
}

// ---------------------------------------------------------------------------
// Kernel 2: fused offset-conv + DCN, one block = 64 consecutive px (same b,y).
// Pipeline per tap (both phases, fully unrolled so LDS buffer indices are
// compile-time): issue gathers for tap k+1 -> regs ; MFMA on Sb[k&1] ;
// combine + ds_write tap k+1 -> Sb[1-(k&1)] ; barrier.
// Bilinear combine is packed f16 whole-vector math (4x v_pk_mul_f16 +
// 12x v_pk_fma_f16 per 16 channels): ~4x fewer VALU insts than the f32
// cvt+fma path, which was the dominant controllable cost.
// ---------------------------------------------------------------------------
__global__ __launch_bounds__(256, 4) void dcn_fused(
    const f16* __restrict__ xt, const f16* __restrict__ wofb,
    const float* __restrict__ b_off, const f16* __restrict__ wtb,
    float* __restrict__ out) {
  __shared__ __align__(16) f16 Sb[2][64 * SR];     // 18432 B
  __shared__ __align__(16) float offL[64 * 18];    //  4608 B

  const int t = threadIdx.x;
  const int pixbase = blockIdx.x * 64;
  const int b = pixbase >> 14;
  const int y = (pixbase & (HWn - 1)) >> 7;
  const int xx0 = pixbase & (Wn - 1);              // 0 or 64
  const f16* xb = xt + (((size_t)b) << 14) * 64;

  const int px_s = t >> 2, cq = t & 3;             // staging role
  const int lane = t & 63, wv = t >> 6;            // gemm role
  const int l15 = lane & 15, q = lane >> 4;

  // ---------------- phase 1: offset GEMM ----------------
  const int m = wv & 1;                            // o-tile (0..1)
  const int nb = (wv >> 1) * 2;                    // first n-tile (0 or 2)

  auto load1 = [&](int k, f16x8& ra, f16x8& rb) {
    const int dy = k / 3 - 1, dx = k % 3 - 1;
    const int ys = y + dy, xs = xx0 + px_s + dx;
    if (ys >= 0 && ys < Hn && xs >= 0 && xs < Wn) {
      const f16* src = xb + (size_t)(ys * Wn + xs) * 64 + cq * 16;
      ra = *(const f16x8*)src;
      rb = *(const f16x8*)(src + 8);
    } else {
      ra = (f16x8){};
      rb = (f16x8){};
    }
  };
  auto write1 = [&](f16x8 ra, f16x8 rb, int buf) {
    f16* sdst = &Sb[buf][px_s * SR + cq * 16];
    *(f16x8*)sdst = ra;
    *(f16x8*)(sdst + 8) = rb;
  };

  f32x4 acc2[2] = {};
  f16x8 af[2], afn[2];
#pragma unroll
  for (int s = 0; s < 2; ++s)
    af[s] = *(const f16x8*)&wofb[(size_t)(m * 16 + l15) * 64 + s * 32 + q * 8];
  {
    f16x8 ra, rb;
    load1(0, ra, rb);
    write1(ra, rb, 0);
  }
  __syncthreads();
#pragma unroll
  for (int k = 0; k < Kn; ++k) {
    const int cur = k & 1;
    f16x8 nra, nrb;
    if (k + 1 < Kn) {
      load1(k + 1, nra, nrb);
#pragma unroll
      for (int s = 0; s < 2; ++s)
        afn[s] = *(const f16x8*)
            &wofb[(size_t)((k + 1) * 32 + m * 16 + l15) * 64 + s * 32 + q * 8];
    }
#pragma unroll
    for (int s = 0; s < 2; ++s) {
#pragma unroll
      for (int t2 = 0; t2 < 2; ++t2) {
        f16x8 bf = *(const f16x8*)
            &Sb[cur][((nb + t2) * 16 + l15) * SR + s * 32 + q * 8];
        acc2[t2] = __builtin_amdgcn_mfma_f32_16x16x32_f16(af[s], bf, acc2[t2],
                                                          0, 0, 0);
      }
    }
    if (k + 1 < Kn) write1(nra, nrb, 1 - cur);
    __syncthreads();
    af[0] = afn[0];
    af[1] = afn[1];
  }

  // phase-1 epilogue: C/D col=lane&15 (px), row=q*4+r (o). Write to LDS.
#pragma unroll
  for (int t2 = 0; t2 < 2; ++t2) {
#pragma unroll
    for (int r = 0; r < 4; ++r) {
      int o = m * 16 + q * 4 + r;
      if (o < 18) {
        int pxl = (nb + t2) * 16 + l15;
        offL[pxl * 18 + o] = acc2[t2][r] + b_off[o];
      }
    }
  }
  __syncthreads();

  // each thread grabs its pixel's 9 offset pairs from LDS
  float2 off9[9];
  {
    const float* op = &offL[px_s * 18];
#pragma unroll
    for (int k = 0; k < Kn; ++k) off9[k] = *(const float2*)(op + 2 * k);
  }

  // ---------------- phase 2: main DCN GEMM ----------------
  const int xx = xx0 + px_s;                      // this thread's pixel x
  const int obase = wv * 16;

  auto load2 = [&](int k, Tap2& tp) {
    const int dy = k / 3 - 1, dx = k % 3 - 1;
    float py = (float)(y + dy) + off9[k].x;
    float pxf = (float)(xx + dx) + off9[k].y;
    float y0f = floorf(py), x0f = floorf(pxf);
    int y0 = (int)y0f, x0 = (int)x0f;
    int y1 = y0 + 1, x1 = x0 + 1;
    float wy1 = py - y0f, wx1 = pxf - x0f;
    float wy0 = 1.f - wy1, wx0 = 1.f - wx1;
    float my0 = (y0 >= 0 && y0 < Hn) ? 1.f : 0.f;
    float my1 = (y1 >= 0 && y1 < Hn) ? 1.f : 0.f;
    float mx0 = (x0 >= 0 && x0 < Wn) ? 1.f : 0.f;
    float mx1 = (x1 >= 0 && x1 < Wn) ? 1.f : 0.f;
    tp.W00 = splat8(wy0 * wx0 * my0 * mx0);
    tp.W01 = splat8(wy0 * wx1 * my0 * mx1);
    tp.W10 = splat8(wy1 * wx0 * my1 * mx0);
    tp.W11 = splat8(wy1 * wx1 * my1 * mx1);
    int cy0 = min(max(y0, 0), Hn - 1), cy1 = min(max(y1, 0), Hn - 1);
    int cx0 = min(max(x0, 0), Wn - 1), cx1 = min(max(x1, 0), Wn - 1);
    const f16* r00 = xb + (size_t)(cy0 * Wn + cx0) * 64 + cq * 16;
    const f16* r01 = xb + (size_t)(cy0 * Wn + cx1) * 64 + cq * 16;
    const f16* r10 = xb + (size_t)(cy1 * Wn + cx0) * 64 + cq * 16;
    const f16* r11 = xb + (size_t)(cy1 * Wn + cx1) * 64 + cq * 16;
    tp.a0 = *(const f16x8*)r00;
    tp.a1 = *(const f16x8*)(r00 + 8);
    tp.b0 = *(const f16x8*)r01;
    tp.b1 = *(const f16x8*)(r01 + 8);
    tp.c0 = *(const f16x8*)r10;
    tp.c1 = *(const f16x8*)(r10 + 8);
    tp.d0 = *(const f16x8*)r11;
    tp.d1 = *(const f16x8*)(r11 + 8);
  };
  auto write2 = [&](const Tap2& tp, int buf) {
    f16* sdst = &Sb[buf][px_s * SR + cq * 16];
    f16x8 v0 = tp.a0 * tp.W00 + tp.b0 * tp.W01 + tp.c0 * tp.W10 +
               tp.d0 * tp.W11;
    f16x8 v1 = tp.a1 * tp.W00 + tp.b1 * tp.W01 + tp.c1 * tp.W10 +
               tp.d1 * tp.W11;
    *(f16x8*)sdst = v0;
    *(f16x8*)(sdst + 8) = v1;
  };

  f32x4 acc[4] = {};
  f16x8 wf[2], wfn[2];
#pragma unroll
  for (int s = 0; s < 2; ++s)
    wf[s] = *(const f16x8*)&wtb[(size_t)(obase + l15) * 64 + s * 32 + q * 8];
  {
    Tap2 tp;
    load2(0, tp);
    write2(tp, 0);
  }
  __syncthreads();
#pragma unroll
  for (int k = 0; k < Kn; ++k) {
    const int cur = k & 1;
    Tap2 tp;
    if (k + 1 < Kn) {
      load2(k + 1, tp);
#pragma unroll
      for (int s = 0; s < 2; ++s)
        wfn[s] = *(const f16x8*)
            &wtb[(size_t)((k + 1) * 64 + obase + l15) * 64 + s * 32 + q * 8];
    }
#pragma unroll
    for (int s = 0; s < 2; ++s) {
#pragma unroll
      for (int pt = 0; pt < 4; ++pt) {
        f16x8 bf =
            *(const f16x8*)&Sb[cur][(pt * 16 + l15) * SR + s * 32 + q * 8];
        acc[pt] = __builtin_amdgcn_mfma_f32_16x16x32_f16(wf[s], bf, acc[pt],
                                                         0, 0, 0);
      }
    }
    if (k + 1 < Kn) write2(tp, 1 - cur);
    __syncthreads();
    wf[0] = wfn[0];
    wf[1] = wfn[1];
  }

  // phase-2 epilogue: C/D layout col=lane&15 (px), row=q*4+reg (o in chunk)
  float* ob = out + (size_t)b * On * HWn + (pixbase & (HWn - 1));
#pragma unroll
  for (int pt = 0; pt < 4; ++pt) {
#pragma unroll
    for (int r = 0; r < 4; ++r) {
      int o = obase + q * 4 + r;
      ob[(size_t)o * HWn + pt * 16 + l15] = acc[pt][r];
    }
  }
}

// ---------------------------------------------------------------------------
extern "C" void kernel_launch(void* const* d_in, const int* in_sizes, int n_in,
                              void* d_out, int out_size, void* d_ws,
                              size_t ws_size, hipStream_t stream) {
  const float* x = (const float*)d_in[0];       // [4,64,128,128]
  const float* w_off = (const float*)d_in[1];   // [18,64,3,3]
  const float* b_off = (const float*)d_in[2];   // [18]
  const float* weight = (const float*)d_in[3];  // [64,64,3,3]
  float* out = (float*)d_out;                   // [4,64,128,128]

  // workspace layout (offset buffer lives in LDS)
  f16* xt = (f16*)d_ws;                         // 4,194,304 f16 = 8 MB
  f16* wtb = xt + (size_t)NPIX * Cn;            // 36,864 f16
  f16* wofb = wtb + Kn * On * Cn;               // 18,432 f16

  transpose_prep<<<dim3(NPIX / 64), dim3(256), 0, stream>>>(x, w_off, weight,
                                                            xt, wofb, wtb);
  dcn_fused<<<dim3(NPIX / 64), dim3(256), 0, stream>>>(xt, wofb, b_off, wtb,
                                                       out);
}